// Round 4
// baseline (1754.480 us; speedup 1.0000x reference)
//
#include <hip/hip_runtime.h>
#include <math.h>

#define TSTEPS 512
#define BN 4096
#define NBLK 128
#define NTHR 256
#define NPB 32        // neurons per block (BN/NBLK)
#define NW  128       // mask words per step (= NBLK), 32 spike bits each
#define WSTRIDE 16    // u64s per mailbox word: 1 word per 128-B cache line

typedef unsigned long long u64;

__device__ __forceinline__ u64 ld_agent(const u64* p) {
    return __hip_atomic_load(p, __ATOMIC_RELAXED, __HIP_MEMORY_SCOPE_AGENT);
}
__device__ __forceinline__ void st_agent(u64* p, u64 v) {
    __hip_atomic_store(p, v, __ATOMIC_RELAXED, __HIP_MEMORY_SCOPE_AGENT);
}

// Persistent kernel, 128 blocks. Per step each block publishes ONE tagged u64
// (tag<<32 | 32-bit spike mask) in its OWN 128-B cache line (no L3 line
// contention between producers; polling storm spreads across 128 lines).
// Wave 0 polls 2 lines/lane (both loads issued per retry), single-wave prefix
// scan builds the compacted active-column list; all 256 threads then run a
// pipelined gather-GEMV (8 threads x float4 per column, 8 columns in flight).
// 2 __syncthreads per step.
template<bool TR>
__global__ __launch_bounds__(NTHR, 1)
void glif_kernel(const float* __restrict__ x_seq, const float* __restrict__ w,
                 const float* __restrict__ b_in, const float* __restrict__ v0,
                 const float* __restrict__ Ia0, const float* __restrict__ vth_in,
                 const float* __restrict__ vrst_in, const float* __restrict__ vrest_in,
                 const float* __restrict__ cm_in, const float* __restrict__ tau_in,
                 const float* __restrict__ k_in, const float* __restrict__ asc_in,
                 const float* __restrict__ mask_in,
                 float* __restrict__ out_s, float* __restrict__ out_v,
                 float* __restrict__ out_vf, float* __restrict__ out_if,
                 u64* __restrict__ sbuf, unsigned* __restrict__ bar,
                 float* __restrict__ wT)
{
    __shared__ float  tile[64][65];    // transpose staging (phase 0 only)
    __shared__ float  maskf[BN];       // spike amplitudes
    __shared__ int    list[BN];        // compacted active column indices
    __shared__ float4 wpart4[4][8];    // per-wave GEMV partials (flat: [4][32] floats)
    __shared__ int    sc_total;

    const int blk = blockIdx.x;
    const int tid = threadIdx.x;
    const int n0 = blk * NPB;
    const int wave = tid >> 6;
    const int lane = tid & 63;

    // ---- Phase 0: transpose w -> wT (active columns become contiguous rows)
    if (TR) {
        for (int tt = 0; tt < 32; ++tt) {
            int tile_id = blk + tt * NBLK;       // 4096 tiles of 64x64
            int ti = tile_id >> 6, tj = tile_id & 63;
            int c = tid & 63, r0 = tid >> 6;
#pragma unroll
            for (int rr = 0; rr < 16; ++rr) {
                int r = r0 + rr * 4;
                tile[r][c] = w[(size_t)(ti * 64 + r) * BN + tj * 64 + c];
            }
            __syncthreads();
            int rw = tid & 63, c0 = tid >> 6;
#pragma unroll
            for (int cc = 0; cc < 16; ++cc) {
                int cw = c0 + cc * 4;
                wT[(size_t)(tj * 64 + cw) * BN + ti * 64 + rw] = tile[rw][cw];
            }
            __syncthreads();
        }
    }

    // stage spike amplitudes in LDS
    for (int i = tid; i < BN; i += NTHR) maskf[i] = mask_in[i];

    // ---- single grid barrier: wT complete before step loop
    __syncthreads();
    if (tid == 0) {
        __threadfence();
        __hip_atomic_fetch_add(bar, 1u, __ATOMIC_ACQ_REL, __HIP_MEMORY_SCOPE_AGENT);
        while (__hip_atomic_load(bar, __ATOMIC_RELAXED, __HIP_MEMORY_SCOPE_AGENT) < NBLK) {
            __builtin_amdgcn_s_sleep(8);
        }
        __threadfence();
    }
    __syncthreads();

    // ---- per-neuron state in registers (threads tid<NPB own neuron n)
    const int n = n0 + tid;
    float v = 0, I0 = 0, I1 = 0, bb = 0, aa = 0, bd0 = 0, bd1 = 0, as0 = 0, as1 = 0,
          vth = 0, vrst = 0, vrest = 0, cm = 1, tau = 1, msk = 0;
    if (tid < NPB) {
        v = v0[n]; I0 = Ia0[2 * n]; I1 = Ia0[2 * n + 1];
        bb = b_in[n]; vth = vth_in[n]; vrst = vrst_in[n]; vrest = vrest_in[n];
        cm = cm_in[n]; tau = tau_in[n]; msk = mask_in[n];
        aa  = (float)exp((double)(-1.0f / tau));
        bd0 = (float)exp((double)(-k_in[2 * n]));
        bd1 = (float)exp((double)(-k_in[2 * n + 1]));
        as0 = asc_in[2 * n]; as1 = asc_in[2 * n + 1];
    }

    const int cslot = tid >> 3;          // 0..31: column slot within a round
    const int lane8 = tid & 7;           // 8 threads per column, float4 each
    const float* wb4 = wT + n0 + lane8 * 4;

    for (int t = 0; t < TSTEPS; ++t) {
        float xt = 0.0f;
        if (tid < NPB) xt = x_seq[(size_t)t * BN + n];   // issue early

        // ---- wave 0: poll 2 mailbox lines per lane (both issued per retry)
        if (wave == 0) {
            const u64* src = sbuf + (size_t)(t & 1) * NW * WSTRIDE;
            const u64* p0 = &src[(size_t)(2 * lane) * WSTRIDE];
            const u64* p1 = &src[(size_t)(2 * lane + 1) * WSTRIDE];
            const unsigned wt = (unsigned)t;
            u64 e0 = ld_agent(p0);
            u64 e1 = ld_agent(p1);
            while (((unsigned)(e0 >> 32) != wt) | ((unsigned)(e1 >> 32) != wt)) {
                __builtin_amdgcn_s_sleep(1);
                e0 = ld_agent(p0);
                e1 = ld_agent(p1);
            }
            unsigned m0 = (unsigned)e0, m1 = (unsigned)e1;
            int c0 = __popc(m0), c1 = __popc(m1);
            int x = c0 + c1;
#pragma unroll
            for (int d = 1; d < 64; d <<= 1) {
                int y = __shfl_up(x, d);
                if (lane >= d) x += y;
            }
            if (lane == 63) sc_total = x;
            int b0 = x - c1 - c0;                 // base for word 2*lane
            int b1 = x - c1;                      // base for word 2*lane+1
            while (m0) { int bp = __ffs(m0) - 1; m0 &= m0 - 1; list[b0++] = (lane << 6) + bp; }
            while (m1) { int bp = __ffs(m1) - 1; m1 &= m1 - 1; list[b1++] = (lane << 6) + 32 + bp; }
        }
        __syncthreads();                          // barrier 1: list + sc_total ready
        const int total = sc_total;

        // ---- pipelined gather-GEMV: 32 columns/round, 8-deep batches
        float4 acc = make_float4(0.f, 0.f, 0.f, 0.f);
        const int R = (total + 31) >> 5;          // rounds of 32 columns
        if (TR) {
            for (int r = 0; r < R; r += 8) {
#pragma unroll
                for (int u = 0; u < 8; ++u) {
                    int idx = (r + u) * 32 + cslot;
                    bool p = idx < total;
                    int j = list[p ? idx : 0];
                    float sj = p ? maskf[j] : 0.0f;
                    const float4 wv = *reinterpret_cast<const float4*>(wb4 + ((size_t)j << 12));
                    acc.x = fmaf(wv.x, sj, acc.x);
                    acc.y = fmaf(wv.y, sj, acc.y);
                    acc.z = fmaf(wv.z, sj, acc.z);
                    acc.w = fmaf(wv.w, sj, acc.w);
                }
            }
        } else {
            const float* r0p = w + (size_t)(n0 + lane8 * 4) * BN;
            for (int r = 0; r < R; r += 4) {
#pragma unroll
                for (int u = 0; u < 4; ++u) {
                    int idx = (r + u) * 32 + cslot;
                    bool p = idx < total;
                    int j = list[p ? idx : 0];
                    float sj = p ? maskf[j] : 0.0f;
                    acc.x = fmaf(r0p[j], sj, acc.x);
                    acc.y = fmaf(r0p[j + (size_t)BN], sj, acc.y);
                    acc.z = fmaf(r0p[j + 2 * (size_t)BN], sj, acc.z);
                    acc.w = fmaf(r0p[j + 3 * (size_t)BN], sj, acc.w);
                }
            }
        }
        // reduce across the 8 column-slots within each wave
#pragma unroll
        for (int d = 8; d < 64; d <<= 1) {
            acc.x += __shfl_xor(acc.x, d);
            acc.y += __shfl_xor(acc.y, d);
            acc.z += __shfl_xor(acc.z, d);
            acc.w += __shfl_xor(acc.w, d);
        }
        if (lane < 8) wpart4[wave][lane] = acc;   // lane == lane8 here
        __syncthreads();                          // barrier 2: partials ready

        // ---- neuron update; publish spike word ASAP, then finish state/stores
        float s = 0.0f;
        float vp = 0.0f;
        if (tid < NPB) {
            const float* wp = reinterpret_cast<const float*>(wpart4);  // [4][32]
            float lin = (wp[tid] + wp[32 + tid]) + (wp[64 + tid] + wp[96 + tid]);
            float xx = (xt + bb) + lin;
            float Isum = I0 + I1;
            float vinf = vrest + (tau * (xx + Isum)) / cm;
            vp = vinf + (v - vinf) * aa;
            float uu = (vp - vth) / (vth - vrst);
            s = (uu > 0.0f) ? msk : 0.0f;
        }
        u64 bal = __ballot(s != 0.0f);            // bits 0..31 valid in wave 0
        if (tid == 0) {
            u64 ent = (((u64)(t + 1)) << 32) | (u64)(unsigned)bal;
            st_agent(&sbuf[((size_t)((t + 1) & 1) * NW + blk) * WSTRIDE], ent);
        }
        if (tid < NPB) {
            float vpost = vp - (vp - vrst) * s;   // HARD_RESET
            I0 = I0 * bd0 + as0 * s;
            I1 = I1 * bd1 + as1 * s;
            v = vpost;
            out_s[(size_t)t * BN + n] = s;
            out_v[(size_t)t * BN + n] = vpost;
        }
    }

    if (tid < NPB) {
        out_vf[n] = v;
        out_if[2 * n] = I0;
        out_if[2 * n + 1] = I1;
    }
}

extern "C" void kernel_launch(void* const* d_in, const int* in_sizes, int n_in,
                              void* d_out, int out_size, void* d_ws, size_t ws_size,
                              hipStream_t stream)
{
    const float* x_seq = (const float*)d_in[0];
    const float* w     = (const float*)d_in[1];
    const float* b     = (const float*)d_in[2];
    const float* v0    = (const float*)d_in[3];
    const float* Ia0   = (const float*)d_in[4];
    const float* vth   = (const float*)d_in[5];
    const float* vrst  = (const float*)d_in[6];
    const float* vrest = (const float*)d_in[7];
    const float* cm    = (const float*)d_in[8];
    const float* tau   = (const float*)d_in[9];
    const float* k     = (const float*)d_in[10];
    const float* asc   = (const float*)d_in[11];
    const float* mask  = (const float*)d_in[12];

    float* out_s  = (float*)d_out;
    float* out_v  = out_s + (size_t)TSTEPS * BN;
    float* out_vf = out_v + (size_t)TSTEPS * BN;
    float* out_if = out_vf + BN;

    // mailbox: 2 parities x 128 blocks x 128-B line = 32 KiB
    const size_t mb_bytes = (size_t)2 * NW * WSTRIDE * sizeof(u64);
    u64* sbuf     = (u64*)d_ws;
    unsigned* bar = (unsigned*)((char*)d_ws + mb_bytes);
    float* wT     = (float*)((char*)d_ws + mb_bytes + 256);

    const size_t need = mb_bytes + 256 + (size_t)BN * BN * sizeof(float);
    const bool tr = (ws_size >= need);

    // zero mailbox tags + barrier counter (inside graph -> resets every replay)
    hipMemsetAsync(d_ws, 0, mb_bytes + 256, stream);

    if (tr) {
        glif_kernel<true><<<NBLK, NTHR, 0, stream>>>(
            x_seq, w, b, v0, Ia0, vth, vrst, vrest, cm, tau, k, asc, mask,
            out_s, out_v, out_vf, out_if, sbuf, bar, wT);
    } else {
        glif_kernel<false><<<NBLK, NTHR, 0, stream>>>(
            x_seq, w, b, v0, Ia0, vth, vrst, vrest, cm, tau, k, asc, mask,
            out_s, out_v, out_vf, out_if, sbuf, bar, (float*)w);
    }
}

// Round 5
// 1708.249 us; speedup vs baseline: 1.0271x; 1.0271x over previous
//
#include <hip/hip_runtime.h>
#include <math.h>

#define TSTEPS 512
#define BN 4096
#define NBLK 64
#define NTHR 512
#define NPB 64        // neurons per block (BN/NBLK)
#define NWAVE 8
#define ESTRIDE 16    // u64s per mailbox entry: one 128-B line per block

typedef unsigned long long u64;

__device__ __forceinline__ u64 ld_agent(const u64* p) {
    return __hip_atomic_load(p, __ATOMIC_RELAXED, __HIP_MEMORY_SCOPE_AGENT);
}
__device__ __forceinline__ void st_agent(u64* p, u64 v) {
    __hip_atomic_store(p, v, __ATOMIC_RELAXED, __HIP_MEMORY_SCOPE_AGENT);
}

// Persistent kernel, 64 blocks x 512 threads (8 waves). Block publishes its
// 64-neuron spike mask as TWO tagged u64 words in its own 128-B line.
// Each wave owns 8 mailbox entries: polls them (4x-redundant lanes, 1 word
// per lane), builds its private compacted column list via in-wave shuffle
// scan, and gathers those columns of the mask-scaled transposed weights --
// all with NO block barrier. One __syncthreads per step (before the update
// combine); GEMV partials are double-buffered so the single-barrier pipeline
// is race-free. Fixed word/bit/tree order => deterministic fp results.
template<bool TR>
__global__ __launch_bounds__(NTHR, 1)
void glif_kernel(const float* __restrict__ x_seq, const float* __restrict__ w,
                 const float* __restrict__ b_in, const float* __restrict__ v0,
                 const float* __restrict__ Ia0, const float* __restrict__ vth_in,
                 const float* __restrict__ vrst_in, const float* __restrict__ vrest_in,
                 const float* __restrict__ cm_in, const float* __restrict__ tau_in,
                 const float* __restrict__ k_in, const float* __restrict__ asc_in,
                 const float* __restrict__ mask_in,
                 float* __restrict__ out_s, float* __restrict__ out_v,
                 float* __restrict__ out_vf, float* __restrict__ out_if,
                 u64* __restrict__ sbuf, unsigned* __restrict__ bar,
                 float* __restrict__ wT)
{
    __shared__ float  tile[64][65];          // transpose staging (phase 0 only)
    __shared__ int    wlist[NWAVE][512];     // per-wave active-column lists
    __shared__ float4 partials[2][NWAVE][16];// double-buffered GEMV partials

    const int blk = blockIdx.x;
    const int tid = threadIdx.x;
    const int n0 = blk * NPB;
    const int wv = tid >> 6;                 // wave 0..7
    const int ln = tid & 63;

    // ---- Phase 0: transpose w -> wT, scaling column j by mask_in[j]
    // (w[n][j]*mask[j] rounds identically to the reference's w @ s product)
    if (TR) {
        for (int tt = 0; tt < 64; ++tt) {
            int tile_id = blk + tt * NBLK;   // 4096 tiles of 64x64
            int ti = tile_id >> 6, tj = tile_id & 63;
            int c = tid & 63, r0 = tid >> 6;
#pragma unroll
            for (int rr = 0; rr < 8; ++rr) {
                int r = r0 + rr * 8;
                tile[r][c] = w[(size_t)(ti * 64 + r) * BN + tj * 64 + c];
            }
            __syncthreads();
            int rw = tid & 63, c0 = tid >> 6;
#pragma unroll
            for (int cc = 0; cc < 8; ++cc) {
                int cw = c0 + cc * 8;
                float mcol = mask_in[tj * 64 + cw];
                wT[(size_t)(tj * 64 + cw) * BN + ti * 64 + rw] = tile[rw][cw] * mcol;
            }
            __syncthreads();
        }
    }

    // ---- single grid barrier: wT complete before step loop
    __syncthreads();
    if (tid == 0) {
        __threadfence();
        __hip_atomic_fetch_add(bar, 1u, __ATOMIC_ACQ_REL, __HIP_MEMORY_SCOPE_AGENT);
        while (__hip_atomic_load(bar, __ATOMIC_RELAXED, __HIP_MEMORY_SCOPE_AGENT) < NBLK) {
            __builtin_amdgcn_s_sleep(8);
        }
        __threadfence();
    }
    __syncthreads();

    // ---- per-neuron state: wave 0's 64 lanes own the block's 64 neurons
    const int n = n0 + tid;
    float v = 0, I0 = 0, I1 = 0, bb = 0, aa = 0, bd0 = 0, bd1 = 0, as0 = 0, as1 = 0,
          vth = 0, vrst = 0, vrest = 0, cm = 1, tau = 1, msk = 0;
    if (tid < NPB) {
        v = v0[n]; I0 = Ia0[2 * n]; I1 = Ia0[2 * n + 1];
        bb = b_in[n]; vth = vth_in[n]; vrst = vrst_in[n]; vrest = vrest_in[n];
        cm = cm_in[n]; tau = tau_in[n]; msk = mask_in[n];
        aa  = (float)exp((double)(-1.0f / tau));
        bd0 = (float)exp((double)(-k_in[2 * n]));
        bd1 = (float)exp((double)(-k_in[2 * n + 1]));
        as0 = asc_in[2 * n]; as1 = asc_in[2 * n + 1];
    }

    // poll geometry: lane ln handles byte `sub` of entry (wv*8+e)'s 64-bit mask
    const int e = ln >> 3;                   // entry within this wave's 8
    const int sub = ln & 7;                  // byte 0..7 of the mask64
    const int wsel = sub >> 2;               // tagged word 0 (bits 0..31) or 1
    const int bshift = 8 * (sub & 3);
    const int cbase = ((wv * 8 + e) << 6) + (sub << 3);  // column of this byte's bit 0

    const int cslot = ln >> 4, l16 = ln & 15;            // GEMV: 4 cols/round, 16 lanes/col
    const float* wb4 = wT + n0 + l16 * 4;

    for (int t = 0; t < TSTEPS; ++t) {
        float xt = 0.0f;
        if (tid < NPB) xt = x_seq[(size_t)t * BN + n];   // issue early

        // ---- poll own word (no block barrier; 4 lanes redundantly per word)
        const u64* p = sbuf + ((size_t)(t & 1) * NBLK + (wv * 8 + e)) * ESTRIDE + wsel;
        const unsigned want = (unsigned)t;
        u64 ev = ld_agent(p);
        while ((unsigned)(ev >> 32) != want) {
            __builtin_amdgcn_s_sleep(1);
            ev = ld_agent(p);
        }
        unsigned byte = ((unsigned)ev >> bshift) & 0xFFu;

        // ---- in-wave compaction (fixed order => deterministic)
        int c = __popc(byte);
        int x = c;
#pragma unroll
        for (int d = 1; d < 64; d <<= 1) {
            int y = __shfl_up(x, d);
            if (ln >= d) x += y;
        }
        const int kw = __shfl(x, 63);
        int base = x - c;
        while (byte) { int bp = __ffs(byte) - 1; byte &= byte - 1; wlist[wv][base++] = cbase + bp; }

        // ---- per-wave gather-GEMV over its own column list (mask pre-folded)
        float4 acc = make_float4(0.f, 0.f, 0.f, 0.f);
        const int R = (kw + 3) >> 2;         // rounds of 4 columns
        if (TR) {
            for (int r = 0; r < R; r += 8) {
#pragma unroll
                for (int u = 0; u < 8; ++u) {
                    int idx = (r + u) * 4 + cslot;
                    bool pg = idx < kw;
                    int j = wlist[wv][pg ? idx : 0];
                    float m = pg ? 1.0f : 0.0f;
                    const float4 wvv = *reinterpret_cast<const float4*>(wb4 + ((size_t)j << 12));
                    acc.x = fmaf(wvv.x, m, acc.x);
                    acc.y = fmaf(wvv.y, m, acc.y);
                    acc.z = fmaf(wvv.z, m, acc.z);
                    acc.w = fmaf(wvv.w, m, acc.w);
                }
            }
#pragma unroll
            for (int d = 16; d < 64; d <<= 1) {
                acc.x += __shfl_xor(acc.x, d);
                acc.y += __shfl_xor(acc.y, d);
                acc.z += __shfl_xor(acc.z, d);
                acc.w += __shfl_xor(acc.w, d);
            }
            if (ln < 16) partials[t & 1][wv][ln] = acc;
        } else {
            // fallback: lane ln owns neuron n0+ln, serial over wave's list
            float accs = 0.f;
            const float* wrow = w + (size_t)(n0 + ln) * BN;
            for (int i = 0; i < kw; ++i) {
                int j = wlist[wv][i];
                accs = fmaf(wrow[j], mask_in[j], accs);
            }
            reinterpret_cast<float*>(&partials[t & 1][wv][0])[ln] = accs;
        }
        __syncthreads();                     // the ONE barrier per step

        // ---- update (wave 0) + publish; other waves roll straight into t+1
        float s = 0.0f;
        if (tid < NPB) {
            const float* pf = reinterpret_cast<const float*>(&partials[t & 1][0][0]);
            float l0 = pf[tid],        l1 = pf[64 + tid],  l2 = pf[128 + tid], l3 = pf[192 + tid];
            float l4 = pf[256 + tid],  l5 = pf[320 + tid], l6 = pf[384 + tid], l7 = pf[448 + tid];
            float lin = ((l0 + l1) + (l2 + l3)) + ((l4 + l5) + (l6 + l7));
            float xx = (xt + bb) + lin;
            float Isum = I0 + I1;
            float vinf = vrest + (tau * (xx + Isum)) / cm;
            float vp = vinf + (v - vinf) * aa;
            float uu = (vp - vth) / (vth - vrst);
            s = (uu > 0.0f) ? msk : 0.0f;
            u64 bal = __ballot(s != 0.0f);   // wave 0: bit l = neuron n0+l
            if (tid == 0) {
                u64 tagw = ((u64)(t + 1)) << 32;
                u64* dst = sbuf + ((size_t)((t + 1) & 1) * NBLK + blk) * ESTRIDE;
                st_agent(dst,     tagw | (u64)(unsigned)bal);
                st_agent(dst + 1, tagw | (u64)(unsigned)(bal >> 32));
            }
            float vpost = vp - (vp - vrst) * s;   // HARD_RESET
            I0 = I0 * bd0 + as0 * s;
            I1 = I1 * bd1 + as1 * s;
            v = vpost;
            out_s[(size_t)t * BN + n] = s;
            out_v[(size_t)t * BN + n] = vpost;
        }
    }

    if (tid < NPB) {
        out_vf[n] = v;
        out_if[2 * n] = I0;
        out_if[2 * n + 1] = I1;
    }
}

extern "C" void kernel_launch(void* const* d_in, const int* in_sizes, int n_in,
                              void* d_out, int out_size, void* d_ws, size_t ws_size,
                              hipStream_t stream)
{
    const float* x_seq = (const float*)d_in[0];
    const float* w     = (const float*)d_in[1];
    const float* b     = (const float*)d_in[2];
    const float* v0    = (const float*)d_in[3];
    const float* Ia0   = (const float*)d_in[4];
    const float* vth   = (const float*)d_in[5];
    const float* vrst  = (const float*)d_in[6];
    const float* vrest = (const float*)d_in[7];
    const float* cm    = (const float*)d_in[8];
    const float* tau   = (const float*)d_in[9];
    const float* k     = (const float*)d_in[10];
    const float* asc   = (const float*)d_in[11];
    const float* mask  = (const float*)d_in[12];

    float* out_s  = (float*)d_out;
    float* out_v  = out_s + (size_t)TSTEPS * BN;
    float* out_vf = out_v + (size_t)TSTEPS * BN;
    float* out_if = out_vf + BN;

    // mailbox: 2 parities x 64 blocks x 128-B line = 16 KiB
    const size_t mb_bytes = (size_t)2 * NBLK * ESTRIDE * sizeof(u64);
    u64* sbuf     = (u64*)d_ws;
    unsigned* bar = (unsigned*)((char*)d_ws + mb_bytes);
    float* wT     = (float*)((char*)d_ws + mb_bytes + 256);

    const size_t need = mb_bytes + 256 + (size_t)BN * BN * sizeof(float);
    const bool tr = (ws_size >= need);

    // zero mailbox tags + barrier counter (inside graph -> resets every replay)
    hipMemsetAsync(d_ws, 0, mb_bytes + 256, stream);

    if (tr) {
        glif_kernel<true><<<NBLK, NTHR, 0, stream>>>(
            x_seq, w, b, v0, Ia0, vth, vrst, vrest, cm, tau, k, asc, mask,
            out_s, out_v, out_vf, out_if, sbuf, bar, wT);
    } else {
        glif_kernel<false><<<NBLK, NTHR, 0, stream>>>(
            x_seq, w, b, v0, Ia0, vth, vrst, vrest, cm, tau, k, asc, mask,
            out_s, out_v, out_vf, out_if, sbuf, bar, (float*)w);
    }
}

// Round 6
// 1655.803 us; speedup vs baseline: 1.0596x; 1.0317x over previous
//
#include <hip/hip_runtime.h>
#include <math.h>

#define TSTEPS 512
#define BN 4096
#define NBLK 64
#define NTHR 576      // 9 waves: wave 0 = updater, waves 1..8 = gather waves
#define NPB 64        // neurons per block
#define NGW 8         // gather waves
#define ESTRIDE 16    // u64s per mailbox entry: one 128-B line per block

typedef unsigned long long u64;

__device__ __forceinline__ u64 ld_agent(const u64* p) {
    return __hip_atomic_load(p, __ATOMIC_RELAXED, __HIP_MEMORY_SCOPE_AGENT);
}
__device__ __forceinline__ void st_agent(u64* p, u64 v) {
    __hip_atomic_store(p, v, __ATOMIC_RELAXED, __HIP_MEMORY_SCOPE_AGENT);
}
__device__ __forceinline__ void st_flag(unsigned* p, unsigned v) {
    __hip_atomic_store(p, v, __ATOMIC_RELEASE, __HIP_MEMORY_SCOPE_WORKGROUP);
}
__device__ __forceinline__ unsigned ld_flag(const unsigned* p) {
    return __hip_atomic_load(p, __ATOMIC_ACQUIRE, __HIP_MEMORY_SCOPE_WORKGROUP);
}

// Persistent kernel, 64 blocks x 576 threads (9 waves).
//  wave 0   : pure updater. Spins on 8 LDS flags (fast local detect), combines
//             partials (fixed tree), updates 64 neurons, publishes 2 tagged
//             mailbox words, stores outputs. Never touches the gather path.
//  waves 1-8: free-running gather waves, NO block barrier in the step loop.
//             Each owns 8 mailbox entries: busy-spin poll (2 loads in flight,
//             no s_sleep), 64-lane scan -> compacted column list, pipelined
//             float4 gather of mask-scaled wT, shfl reduce, write partials
//             into a 4-deep LDS ring, release a monotonic LDS flag, roll on.
// Race-freedom: publish(t+1) by any block requires all its gather waves to
// have flagged t, which requires their reads of mailbox step t-1..t done;
// global publish(t+1) therefore orders after every consumer read of t-1,
// so 2-parity mailbox + 4-deep partials ring cannot be overwritten early.
template<bool TR>
__global__ __launch_bounds__(NTHR, 1)
void glif_kernel(const float* __restrict__ x_seq, const float* __restrict__ w,
                 const float* __restrict__ b_in, const float* __restrict__ v0,
                 const float* __restrict__ Ia0, const float* __restrict__ vth_in,
                 const float* __restrict__ vrst_in, const float* __restrict__ vrest_in,
                 const float* __restrict__ cm_in, const float* __restrict__ tau_in,
                 const float* __restrict__ k_in, const float* __restrict__ asc_in,
                 const float* __restrict__ mask_in,
                 float* __restrict__ out_s, float* __restrict__ out_v,
                 float* __restrict__ out_vf, float* __restrict__ out_if,
                 u64* __restrict__ sbuf, unsigned* __restrict__ bar,
                 float* __restrict__ wT)
{
    __shared__ float    tile[64][65];          // transpose staging (phase 0)
    __shared__ int      wlist[NGW][512];       // per-gather-wave column lists
    __shared__ float4   partials[4][NGW][16];  // 4-deep ring of GEMV partials
    __shared__ unsigned flags[NGW];            // monotonic step tags

    const int blk = blockIdx.x;
    const int tid = threadIdx.x;
    const int n0 = blk * NPB;
    const int wv = tid >> 6;                   // wave 0..8
    const int ln = tid & 63;

    // ---- Phase 0: transpose w -> wT, folding mask into columns
    // (w[n][j]*mask[j] rounds identically to the reference's product w/ s=mask)
    if (TR) {
        for (int tt = 0; tt < 64; ++tt) {
            int tile_id = blk + tt * NBLK;     // 4096 tiles of 64x64
            int ti = tile_id >> 6, tj = tile_id & 63;
            if (tid < 512) {
                int c = tid & 63, r0 = tid >> 6;
#pragma unroll
                for (int rr = 0; rr < 8; ++rr) {
                    int r = r0 + rr * 8;
                    tile[r][c] = w[(size_t)(ti * 64 + r) * BN + tj * 64 + c];
                }
            }
            __syncthreads();
            if (tid < 512) {
                int rw = tid & 63, c0 = tid >> 6;
#pragma unroll
                for (int cc = 0; cc < 8; ++cc) {
                    int cw = c0 + cc * 8;
                    float mcol = mask_in[tj * 64 + cw];
                    wT[(size_t)(tj * 64 + cw) * BN + ti * 64 + rw] = tile[rw][cw] * mcol;
                }
            }
            __syncthreads();
        }
    }

    if (tid < NGW) flags[tid] = 0;

    // ---- single grid barrier: wT complete before step loop
    __syncthreads();
    if (tid == 0) {
        __threadfence();
        __hip_atomic_fetch_add(bar, 1u, __ATOMIC_ACQ_REL, __HIP_MEMORY_SCOPE_AGENT);
        while (__hip_atomic_load(bar, __ATOMIC_RELAXED, __HIP_MEMORY_SCOPE_AGENT) < NBLK) {
            __builtin_amdgcn_s_sleep(8);
        }
        __threadfence();
    }
    __syncthreads();

    if (wv == 0) {
        // ================= WAVE 0: pure updater =================
        const int n = n0 + ln;
        float v, I0, I1, bb, aa, bd0, bd1, as0, as1, vth, vrst, vrest, cm, tau, msk;
        v = v0[n]; I0 = Ia0[2 * n]; I1 = Ia0[2 * n + 1];
        bb = b_in[n]; vth = vth_in[n]; vrst = vrst_in[n]; vrest = vrest_in[n];
        cm = cm_in[n]; tau = tau_in[n]; msk = mask_in[n];
        aa  = (float)exp((double)(-1.0f / tau));
        bd0 = (float)exp((double)(-k_in[2 * n]));
        bd1 = (float)exp((double)(-k_in[2 * n + 1]));
        as0 = asc_in[2 * n]; as1 = asc_in[2 * n + 1];

        for (int t = 0; t < TSTEPS; ++t) {
            float xt = x_seq[(size_t)t * BN + n];       // overlaps flag wait

            if (ln < NGW) {                             // fast local detect
                const unsigned want = (unsigned)(t + 1);
                while (ld_flag(&flags[ln]) < want) {}
            }
            // wave reconverged: all 8 partial sets for step t are in LDS
            const float* pf = reinterpret_cast<const float*>(&partials[t & 3][0][0]);
            float l0 = pf[ln],        l1 = pf[64 + ln],  l2 = pf[128 + ln], l3 = pf[192 + ln];
            float l4 = pf[256 + ln],  l5 = pf[320 + ln], l6 = pf[384 + ln], l7 = pf[448 + ln];
            float lin = ((l0 + l1) + (l2 + l3)) + ((l4 + l5) + (l6 + l7));
            float xx = (xt + bb) + lin;
            float Isum = I0 + I1;
            float vinf = vrest + (tau * (xx + Isum)) / cm;
            float vp = vinf + (v - vinf) * aa;
            float uu = (vp - vth) / (vth - vrst);
            float s = (uu > 0.0f) ? msk : 0.0f;
            u64 bal = __ballot(s != 0.0f);              // bit l = neuron n0+l
            u64 tagw = ((u64)(t + 1)) << 32;
            u64* dst = sbuf + ((size_t)((t + 1) & 1) * NBLK + blk) * ESTRIDE;
            if (ln < 2) st_agent(dst + ln, tagw | (u64)(unsigned)(bal >> (32 * ln)));
            float vpost = vp - (vp - vrst) * s;         // HARD_RESET
            I0 = I0 * bd0 + as0 * s;
            I1 = I1 * bd1 + as1 * s;
            v = vpost;
            out_s[(size_t)t * BN + n] = s;
            out_v[(size_t)t * BN + n] = vpost;
        }
        out_vf[n] = v;
        out_if[2 * n] = I0;
        out_if[2 * n + 1] = I1;
    } else {
        // ================= WAVES 1..8: free-running gather =================
        const int gw = wv - 1;
        const int e = ln >> 3;                  // entry within this wave's 8
        const int sub = ln & 7;                 // byte 0..7 of the 64-bit mask
        const int wsel = sub >> 2;              // tagged word 0 or 1
        const int bshift = 8 * (sub & 3);
        const int entry = gw * 8 + e;
        const int cbase = (entry << 6) + (sub << 3);
        const int cslot = ln >> 4, l16 = ln & 15;  // 4 cols/round, 16 lanes/col
        const float* wb4 = wT + n0 + l16 * 4;

        for (int t = 0; t < TSTEPS; ++t) {
            // ---- busy-spin poll, 2 loads in flight, no sleep
            const u64* p = sbuf + ((size_t)(t & 1) * NBLK + entry) * ESTRIDE + wsel;
            const unsigned want = (unsigned)t;
            u64 ev;
            for (;;) {
                u64 A = ld_agent(p);
                u64 B = ld_agent(p);
                if ((unsigned)(A >> 32) == want) { ev = A; break; }
                if ((unsigned)(B >> 32) == want) { ev = B; break; }
            }
            unsigned byte = ((unsigned)ev >> bshift) & 0xFFu;

            // ---- in-wave compaction (fixed order => deterministic)
            int c = __popc(byte);
            int x = c;
#pragma unroll
            for (int d = 1; d < 64; d <<= 1) {
                int y = __shfl_up(x, d);
                if (ln >= d) x += y;
            }
            const int kw = __shfl(x, 63);
            int base = x - c;
            while (byte) { int bp = __ffs(byte) - 1; byte &= byte - 1; wlist[gw][base++] = cbase + bp; }

            // ---- pipelined gather-GEMV over this wave's columns
            if (TR) {
                float4 acc = make_float4(0.f, 0.f, 0.f, 0.f);
                const int R = (kw + 3) >> 2;     // rounds of 4 columns
                for (int r = 0; r < R; r += 8) {
#pragma unroll
                    for (int u = 0; u < 8; ++u) {
                        int idx = (r + u) * 4 + cslot;
                        bool pg = idx < kw;
                        int j = wlist[gw][pg ? idx : 0];
                        float m = pg ? 1.0f : 0.0f;
                        const float4 wvv = *reinterpret_cast<const float4*>(wb4 + ((size_t)j << 12));
                        acc.x = fmaf(wvv.x, m, acc.x);
                        acc.y = fmaf(wvv.y, m, acc.y);
                        acc.z = fmaf(wvv.z, m, acc.z);
                        acc.w = fmaf(wvv.w, m, acc.w);
                    }
                }
#pragma unroll
                for (int d = 16; d < 64; d <<= 1) {
                    acc.x += __shfl_xor(acc.x, d);
                    acc.y += __shfl_xor(acc.y, d);
                    acc.z += __shfl_xor(acc.z, d);
                    acc.w += __shfl_xor(acc.w, d);
                }
                if (ln < 16) partials[t & 3][gw][ln] = acc;
            } else {
                float accs = 0.f;
                const float* wrow = w + (size_t)(n0 + ln) * BN;
                for (int i = 0; i < kw; ++i) {
                    int j = wlist[gw][i];
                    accs = fmaf(wrow[j], mask_in[j], accs);
                }
                reinterpret_cast<float*>(&partials[t & 3][gw][0])[ln] = accs;
            }
            if (ln == 0) st_flag(&flags[gw], (unsigned)(t + 1));  // release
        }
    }
}

extern "C" void kernel_launch(void* const* d_in, const int* in_sizes, int n_in,
                              void* d_out, int out_size, void* d_ws, size_t ws_size,
                              hipStream_t stream)
{
    const float* x_seq = (const float*)d_in[0];
    const float* w     = (const float*)d_in[1];
    const float* b     = (const float*)d_in[2];
    const float* v0    = (const float*)d_in[3];
    const float* Ia0   = (const float*)d_in[4];
    const float* vth   = (const float*)d_in[5];
    const float* vrst  = (const float*)d_in[6];
    const float* vrest = (const float*)d_in[7];
    const float* cm    = (const float*)d_in[8];
    const float* tau   = (const float*)d_in[9];
    const float* k     = (const float*)d_in[10];
    const float* asc   = (const float*)d_in[11];
    const float* mask  = (const float*)d_in[12];

    float* out_s  = (float*)d_out;
    float* out_v  = out_s + (size_t)TSTEPS * BN;
    float* out_vf = out_v + (size_t)TSTEPS * BN;
    float* out_if = out_vf + BN;

    // mailbox: 2 parities x 64 blocks x 128-B line = 16 KiB
    const size_t mb_bytes = (size_t)2 * NBLK * ESTRIDE * sizeof(u64);
    u64* sbuf     = (u64*)d_ws;
    unsigned* bar = (unsigned*)((char*)d_ws + mb_bytes);
    float* wT     = (float*)((char*)d_ws + mb_bytes + 256);

    const size_t need = mb_bytes + 256 + (size_t)BN * BN * sizeof(float);
    const bool tr = (ws_size >= need);

    // zero mailbox tags + barrier counter (inside graph -> resets every replay)
    hipMemsetAsync(d_ws, 0, mb_bytes + 256, stream);

    if (tr) {
        glif_kernel<true><<<NBLK, NTHR, 0, stream>>>(
            x_seq, w, b, v0, Ia0, vth, vrst, vrest, cm, tau, k, asc, mask,
            out_s, out_v, out_vf, out_if, sbuf, bar, wT);
    } else {
        glif_kernel<false><<<NBLK, NTHR, 0, stream>>>(
            x_seq, w, b, v0, Ia0, vth, vrst, vrest, cm, tau, k, asc, mask,
            out_s, out_v, out_vf, out_if, sbuf, bar, (float*)w);
    }
}